// Round 16
// baseline (344.715 us; speedup 1.0000x reference)
//
#include <hip/hip_runtime.h>

// ---------------------------------------------------------------------------
// RNN-T Joint Network, MI355X (gfx950)
//   f  = enc  @ W_enc^T   : [2048 x 640]
//   g  = pred @ W_pred^T  : [ 512 x 640]
//   out[b,t,u,v] = sum_j tanh(f[bt,j] + g[bu,j]) * W_out[v,j] + b_out[v]
// R16 = R9 (best, 285.6us) with BK 32->64: 10 K-steps, ONE vmcnt-draining
// __syncthreads each (R9 had 20) -> half the barrier-drain stalls, 64 MFMA
// per wave between drains (was 32).
//   LDS exactly 160KB: Bsh[2buf][2khalf][32seg x 512] = 128KB (pre-tiled Wh,
//   coalesced gll + identity conflict-free ds_read), Ash[2buf][2khalf][4096]
//   = 32KB, A fully identity: thread t writes slot t (t*16B, coalesced,
//   conflict-free); read af = seg(wm*4+mf), slot lane -> identity.
//   Per-iter: f/g loads FIRST -> 8 glls (B next) -> tanh x16 -> ds_write A
//   (next buf; no fence needed) -> khalf0 reads+32 MFMA (setprio) -> khalf1
//   reads+32 MFMA -> __syncthreads.  1 block/CU, 2 waves/SIMD, grid 2048.
// ---------------------------------------------------------------------------

typedef _Float16 f16x8 __attribute__((ext_vector_type(8)));
typedef float    f32x4 __attribute__((ext_vector_type(4)));

__device__ __forceinline__ float fast_tanh(float x) {
    float e = __builtin_amdgcn_exp2f(x * 2.88539008177792681472f);
    return 1.0f - 2.0f * __builtin_amdgcn_rcpf(e + 1.0f);
}

__device__ __forceinline__ void gll16(const void* g, void* l) {
    __builtin_amdgcn_global_load_lds(
        (const __attribute__((address_space(1))) void*)g,
        (__attribute__((address_space(3))) void*)l, 16, 0, 0);
}

// ---------------------------------------------------------------------------
// Kernel 1: fg GEMM (fp32, exact). W staged transposed -> broadcast reads.
// ---------------------------------------------------------------------------
__global__ __launch_bounds__(256) void fg_kernel(
    const float* __restrict__ enc, const float* __restrict__ pred,
    const float* __restrict__ Wenc, const float* __restrict__ Wpred,
    float* __restrict__ fg)
{
    __shared__ float As[64][36];
    __shared__ float WsT[32][68];

    const int bid = blockIdx.x;
    const int mt = bid / 10;
    const int nt = bid % 10;
    const int m0 = mt * 64;
    const int n0 = nt * 64;

    const float* Aptr;
    const float* Wptr;
    if (m0 < 2048) { Aptr = enc  + (size_t)m0 * 512;          Wptr = Wenc; }
    else           { Aptr = pred + (size_t)(m0 - 2048) * 512; Wptr = Wpred; }

    const int t  = threadIdx.x;
    const int ty = t >> 4;
    const int tx = t & 15;
    const int lr = t >> 2;
    const int lc = (t & 3) * 8;
    const int lane6 = t & 63;
    const int w8    = (t >> 6) * 8;

    float acc[4][4];
#pragma unroll
    for (int i = 0; i < 4; ++i)
#pragma unroll
        for (int j = 0; j < 4; ++j) acc[i][j] = 0.0f;

    for (int k0 = 0; k0 < 512; k0 += 32) {
        __syncthreads();
        {
            const float* sa = Aptr + (size_t)lr * 512 + k0 + lc;
            f32x4 a0 = *(const f32x4*)(sa);
            f32x4 a1 = *(const f32x4*)(sa + 4);
            *(f32x4*)&As[lr][lc]     = a0;
            *(f32x4*)&As[lr][lc + 4] = a1;
            const float* sw = Wptr + (size_t)(n0 + lane6) * 512 + k0 + w8;
            f32x4 w0 = *(const f32x4*)(sw);
            f32x4 w1 = *(const f32x4*)(sw + 4);
#pragma unroll
            for (int j = 0; j < 4; ++j) {
                WsT[w8 + j][lane6]     = w0[j];
                WsT[w8 + 4 + j][lane6] = w1[j];
            }
        }
        __syncthreads();
#pragma unroll
        for (int kk = 0; kk < 32; ++kk) {
            float av[4], bv[4];
#pragma unroll
            for (int i = 0; i < 4; ++i) av[i] = As[ty * 4 + i][kk];
#pragma unroll
            for (int j = 0; j < 4; ++j) bv[j] = WsT[kk][tx * 4 + j];
#pragma unroll
            for (int i = 0; i < 4; ++i)
#pragma unroll
                for (int j = 0; j < 4; ++j)
                    acc[i][j] = fmaf(av[i], bv[j], acc[i][j]);
        }
    }

#pragma unroll
    for (int i = 0; i < 4; ++i) {
        f32x4 v = { acc[i][0], acc[i][1], acc[i][2], acc[i][3] };
        *(f32x4*)&fg[(size_t)(m0 + ty * 4 + i) * 640 + n0 + tx * 4] = v;
    }
}

// ---------------------------------------------------------------------------
// Kernel 2: W_out fp32 [1024][640] -> fp16 tiled [seg][kc][L][8]:
// offset = seg*10240 + kc*512 + L*8, seg=n>>4, kc=k>>5, L=(n&15)+16*((k>>3)&3)
// -> 64-lane gll at base+lane*8 reads contiguous 1KB; slot L = what the MFMA
// B-fragment wants at lane L (identity, zero-conflict ds_read).
// ---------------------------------------------------------------------------
__global__ __launch_bounds__(256) void wconv_kernel(
    const float* __restrict__ W, _Float16* __restrict__ Wh)
{
    const int tid = blockIdx.x * 256 + threadIdx.x;    // 81920
    const int n   = tid / 80;
    const int c   = tid % 80;
    f32x4 a = *(const f32x4*)(W + (size_t)n * 640 + c * 8);
    f32x4 b = *(const f32x4*)(W + (size_t)n * 640 + c * 8 + 4);
    f16x8 h;
#pragma unroll
    for (int j = 0; j < 4; ++j) { h[j] = (_Float16)a[j]; h[4 + j] = (_Float16)b[j]; }
    const int seg = n >> 4;
    const int kc  = c >> 2;
    const int L   = (n & 15) + 16 * (c & 3);
    *(f16x8*)(Wh + (size_t)seg * 10240 + kc * 512 + L * 8) = h;
}

// ---------------------------------------------------------------------------
// Kernel 3: fused tanh + big GEMM.  BM=128, BN=512, BK=64, 512 thr = 8 waves
// (wm=wid&1: 64-row half; wn=wid>>1: 128-col quarter), per-wave 64x128
// (4x8 frags, 128 AGPR). 10 K-steps, one __syncthreads each.
// ---------------------------------------------------------------------------
__global__ __launch_bounds__(512, 2) void joint_kernel(
    const float* __restrict__ fg, const _Float16* __restrict__ Wh,
    const float* __restrict__ bias, float* __restrict__ out)
{
    __shared__ _Float16 Ash[2][2][4096];    // [buf][khalf][8seg*64slot*8] 32KB
    __shared__ _Float16 Bsh[2][2][16384];   // [buf][khalf][32seg*512]    128KB

    const int bid = blockIdx.x;             // 2048
    const int pp  = bid >> 1;               // 1024 m-tiles
    const int mt  = (pp & 7) * 128 + (pp >> 3);   // XCD-chunked (bijective)
    const int nt  = bid & 1;
    const int m0  = mt << 7;

    const int t    = threadIdx.x;
    const int lane = t & 63;
    const int wid  = t >> 6;
    const int wm   = wid & 1;               // m half (64 rows)
    const int wn   = wid >> 1;              // n quarter (128 cols)
    const int lr   = lane & 15;
    const int lk   = lane >> 4;

    // stage-A identity mapping: thread t owns LDS slot t of each khalf:
    //   row = (t>>6)*16 + (t&15), k-chunk8 = (t>>4)&3
    const int arow = ((t >> 6) << 4) + (t & 15);
    const int akc8 = (t >> 4) & 3;
    const int m    = m0 + arow;
    const float* grow = fg + (size_t)(2048 + ((m >> 14) << 6) + (m & 63)) * 640;
    const float* frow = fg + (size_t)(m >> 6) * 640;
    const int aw = t * 8;                   // A write offset (f16 elems)

    // gll: wave wid stages local segs wid*4..wid*4+3, both k-halves
    const _Float16* gbase = Wh + (size_t)(nt * 32 + wid * 4) * 10240 + lane * 8;
    const int gdl = (wid * 4) * 512;        // local dst base (f16)

    f32x4 acc[4][8];
#pragma unroll
    for (int i = 0; i < 4; ++i)
#pragma unroll
        for (int j = 0; j < 8; ++j) acc[i][j] = (f32x4){0.f, 0.f, 0.f, 0.f};

    // ---- prologue: stage K-step 0 into buf 0 ----
    {
        const int kb = 0;
        f32x4 fva = *(const f32x4*)(frow + kb + akc8 * 8);
        f32x4 fvb = *(const f32x4*)(frow + kb + akc8 * 8 + 4);
        f32x4 fvc = *(const f32x4*)(frow + kb + 32 + akc8 * 8);
        f32x4 fvd = *(const f32x4*)(frow + kb + 32 + akc8 * 8 + 4);
        f32x4 gva = *(const f32x4*)(grow + kb + akc8 * 8);
        f32x4 gvb = *(const f32x4*)(grow + kb + akc8 * 8 + 4);
        f32x4 gvc = *(const f32x4*)(grow + kb + 32 + akc8 * 8);
        f32x4 gvd = *(const f32x4*)(grow + kb + 32 + akc8 * 8 + 4);
#pragma unroll
        for (int h = 0; h < 2; ++h)
#pragma unroll
            for (int i = 0; i < 4; ++i)
                gll16(gbase + (size_t)i * 10240 + (0 + h) * 512,
                      &Bsh[0][h][gdl + i * 512]);
        f16x8 h0, h1;
#pragma unroll
        for (int j = 0; j < 4; ++j) {
            h0[j]     = (_Float16)fast_tanh(fva[j] + gva[j]);
            h0[4 + j] = (_Float16)fast_tanh(fvb[j] + gvb[j]);
            h1[j]     = (_Float16)fast_tanh(fvc[j] + gvc[j]);
            h1[4 + j] = (_Float16)fast_tanh(fvd[j] + gvd[j]);
        }
        *(f16x8*)&Ash[0][0][aw] = h0;
        *(f16x8*)&Ash[0][1][aw] = h1;
        __syncthreads();
    }

#define JITER_FULL(KT, B_, NB_)                                                \
    {                                                                          \
        const int kb_ = ((KT) + 1) * 64;                                       \
        const int kc_ = ((KT) + 1) * 2;                                        \
        /* f/g loads FIRST: tanh waits vmcnt(8), glls stay in flight */        \
        f32x4 fva = *(const f32x4*)(frow + kb_ + akc8 * 8);                    \
        f32x4 fvb = *(const f32x4*)(frow + kb_ + akc8 * 8 + 4);                \
        f32x4 fvc = *(const f32x4*)(frow + kb_ + 32 + akc8 * 8);               \
        f32x4 fvd = *(const f32x4*)(frow + kb_ + 32 + akc8 * 8 + 4);           \
        f32x4 gva = *(const f32x4*)(grow + kb_ + akc8 * 8);                    \
        f32x4 gvb = *(const f32x4*)(grow + kb_ + akc8 * 8 + 4);                \
        f32x4 gvc = *(const f32x4*)(grow + kb_ + 32 + akc8 * 8);               \
        f32x4 gvd = *(const f32x4*)(grow + kb_ + 32 + akc8 * 8 + 4);           \
        _Pragma("unroll")                                                      \
        for (int h = 0; h < 2; ++h)                                            \
            _Pragma("unroll")                                                  \
            for (int i = 0; i < 4; ++i)                                        \
                gll16(gbase + (size_t)i * 10240 + (kc_ + h) * 512,             \
                      &Bsh[NB_][h][gdl + i * 512]);                            \
        f16x8 h0, h1;                                                          \
        _Pragma("unroll")                                                      \
        for (int j = 0; j < 4; ++j) {                                          \
            h0[j]     = (_Float16)fast_tanh(fva[j] + gva[j]);                  \
            h0[4 + j] = (_Float16)fast_tanh(fvb[j] + gvb[j]);                  \
            h1[j]     = (_Float16)fast_tanh(fvc[j] + gvc[j]);                  \
            h1[4 + j] = (_Float16)fast_tanh(fvd[j] + gvd[j]);                  \
        }                                                                      \
        *(f16x8*)&Ash[NB_][0][aw] = h0;                                        \
        *(f16x8*)&Ash[NB_][1][aw] = h1;                                        \
        /* khalf 0 */                                                          \
        {                                                                      \
            f16x8 af[4], bf[8];                                                \
            _Pragma("unroll")                                                  \
            for (int mf = 0; mf < 4; ++mf)                                     \
                af[mf] = *(const f16x8*)                                       \
                    &Ash[B_][0][(wm * 4 + mf) * 512 + lane * 8];               \
            _Pragma("unroll")                                                  \
            for (int nf = 0; nf < 8; ++nf)                                     \
                bf[nf] = *(const f16x8*)                                       \
                    &Bsh[B_][0][(wn * 8 + nf) * 512 + lane * 8];               \
            __builtin_amdgcn_s_setprio(1);                                     \
            _Pragma("unroll")                                                  \
            for (int mf = 0; mf < 4; ++mf)                                     \
                _Pragma("unroll")                                              \
                for (int nf = 0; nf < 8; ++nf)                                 \
                    acc[mf][nf] = __builtin_amdgcn_mfma_f32_16x16x32_f16(      \
                        af[mf], bf[nf], acc[mf][nf], 0, 0, 0);                 \
            __builtin_amdgcn_s_setprio(0);                                     \
        }                                                                      \
        /* khalf 1 */                                                          \
        {                                                                      \
            f16x8 af[4], bf[8];                                                \
            _Pragma("unroll")                                                  \
            for (int mf = 0; mf < 4; ++mf)                                     \
                af[mf] = *(const f16x8*)                                       \
                    &Ash[B_][1][(wm * 4 + mf) * 512 + lane * 8];               \
            _Pragma("unroll")                                                  \
            for (int nf = 0; nf < 8; ++nf)                                     \
                bf[nf] = *(const f16x8*)                                       \
                    &Bsh[B_][1][(wn * 8 + nf) * 512 + lane * 8];               \
            __builtin_amdgcn_s_setprio(1);                                     \
            _Pragma("unroll")                                                  \
            for (int mf = 0; mf < 4; ++mf)                                     \
                _Pragma("unroll")                                              \
                for (int nf = 0; nf < 8; ++nf)                                 \
                    acc[mf][nf] = __builtin_amdgcn_mfma_f32_16x16x32_f16(      \
                        af[mf], bf[nf], acc[mf][nf], 0, 0, 0);                 \
            __builtin_amdgcn_s_setprio(0);                                     \
        }                                                                      \
        __syncthreads();                                                       \
    }

#define JITER_LAST(B_)                                                         \
    _Pragma("unroll")                                                          \
    for (int h = 0; h < 2; ++h) {                                              \
        f16x8 af[4], bf[8];                                                    \
        _Pragma("unroll")                                                      \
        for (int mf = 0; mf < 4; ++mf)                                         \
            af[mf] = *(const f16x8*)                                           \
                &Ash[B_][h][(wm * 4 + mf) * 512 + lane * 8];                   \
        _Pragma("unroll")                                                      \
        for (int nf = 0; nf < 8; ++nf)                                         \
            bf[nf] = *(const f16x8*)                                           \
                &Bsh[B_][h][(wn * 8 + nf) * 512 + lane * 8];                   \
        __builtin_amdgcn_s_setprio(1);                                         \
        _Pragma("unroll")                                                      \
        for (int mf = 0; mf < 4; ++mf)                                         \
            _Pragma("unroll")                                                  \
            for (int nf = 0; nf < 8; ++nf)                                     \
                acc[mf][nf] = __builtin_amdgcn_mfma_f32_16x16x32_f16(          \
                    af[mf], bf[nf], acc[mf][nf], 0, 0, 0);                     \
        __builtin_amdgcn_s_setprio(0);                                         \
    }

    for (int kt = 0; kt < 8; kt += 2) {
        JITER_FULL(kt,     0, 1);
        JITER_FULL(kt + 1, 1, 0);
    }
    JITER_FULL(8, 0, 1);                    // computes kt=8, stages kt=9
    JITER_LAST(1);                          // computes kt=9

#undef JITER_FULL
#undef JITER_LAST

    // ---- epilogue: + bias, cached fp32 stores (exact 524 MB total) ----
    float bv[8];
#pragma unroll
    for (int nf = 0; nf < 8; ++nf)
        bv[nf] = bias[nt * 512 + wn * 128 + nf * 16 + lr];

#pragma unroll
    for (int mf = 0; mf < 4; ++mf) {
#pragma unroll
        for (int rr = 0; rr < 4; ++rr) {
            const int row = m0 + wm * 64 + mf * 16 + lk * 4 + rr;
            float* orow = out + (size_t)row * 1024 + nt * 512 + wn * 128;
#pragma unroll
            for (int nf = 0; nf < 8; ++nf)
                orow[nf * 16 + lr] = acc[mf][nf][rr] + bv[nf];
        }
    }
}

// ---------------------------------------------------------------------------
extern "C" void kernel_launch(void* const* d_in, const int* in_sizes, int n_in,
                              void* d_out, int out_size, void* d_ws, size_t ws_size,
                              hipStream_t stream) {
    const float* enc   = (const float*)d_in[0];   // [8,256,512]
    const float* pred  = (const float*)d_in[1];   // [8,64,512]
    const float* Wenc  = (const float*)d_in[2];   // [640,512]
    const float* Wpred = (const float*)d_in[3];   // [640,512]
    const float* Wout  = (const float*)d_in[4];   // [1024,640]
    const float* bout  = (const float*)d_in[5];   // [1024]

    float*     fg = (float*)d_ws;                              // 2560*640 fp32
    _Float16*  Wh = (_Float16*)((char*)d_ws + 2560 * 640 * 4); // tiled 1.25MB

    fg_kernel<<<400, 256, 0, stream>>>(enc, pred, Wenc, Wpred, fg);
    wconv_kernel<<<320, 256, 0, stream>>>(Wout, Wh);
    joint_kernel<<<2048, 512, 0, stream>>>(fg, Wh, bout, (float*)d_out);
}